// Round 1
// 70389.807 us; speedup vs baseline: 4.3745x; 4.3745x over previous
//
#include <hip/hip_runtime.h>

// Problem constants
#define NS   8192          // samples
#define RD   32            // rule dim
#define ED   1024          // embedding dim E
#define HD   1024          // hidden dim H
#define G4   4096          // 4*H (gate rows)
#define TT   (NS * 3)      // total sequential LSTM steps = 24576
#define NBLK 128           // persistent blocks in RNN phase (co-resident on 256 CUs)
#define RING 8             // h ring depth (block skew is provably <= 1)

// padded LDS index: +4 dwords per 16 so ds_read_b128 at lane*20 dwords
// spreads over all 32 banks (8 lanes/bank = b128 minimum, conflict-free)
#define PAD(e) ((e) + (((e) >> 4) << 2))

__device__ __forceinline__ float sigm(float x) {
  return 1.0f / (1.0f + __expf(-x));     // x<<0: expf->inf -> 0, safe
}
__device__ __forceinline__ float tanh_(float x) {
  float ax = fabsf(x);
  float e  = __expf(-2.0f * ax);         // bounded (0,1]
  float t  = (1.0f - e) / (1.0f + e);
  return x < 0.0f ? -t : t;
}

// ---------------------------------------------------------------------------
// Kernel A: fold rule path.  MT[j][r] = sum_e W_rule[r][e]*W_ih[j][e]
//           bias0[j] = b_rule@W_ih[j] + b_ih[j] + b_hh[j];  bias12[j] = b_ih+b_hh
// Also clears the h-ring tags (8192 x 8B) so no stale tags across launches.
// ---------------------------------------------------------------------------
__global__ __launch_bounds__(256) void prep_kernel(
    const float* __restrict__ W_rule, const float* __restrict__ b_rule,
    const float* __restrict__ W_ih,  const float* __restrict__ b_ih,
    const float* __restrict__ b_hh,
    float* __restrict__ MT, float* __restrict__ bias0, float* __restrict__ bias12,
    unsigned long long* __restrict__ ring)
{
  int j = blockIdx.x * 256 + threadIdx.x;   // 0..4095
  // ring clear: 8192 entries, 2 per thread (visible to rnn via kernel-boundary release)
  ring[(size_t)j * 2]     = 0ull;
  ring[(size_t)j * 2 + 1] = 0ull;

  float acc[RD];
  #pragma unroll
  for (int r = 0; r < RD; r++) acc[r] = 0.0f;
  float accb = 0.0f;
  const float* wrow = W_ih + (size_t)j * ED;
  for (int e = 0; e < ED; e += 4) {
    float4 w4 = *(const float4*)(wrow + e);
    float4 br = *(const float4*)(b_rule + e);
    accb += w4.x * br.x + w4.y * br.y + w4.z * br.z + w4.w * br.w;
    #pragma unroll
    for (int r = 0; r < RD; r++) {
      float4 a4 = *(const float4*)(W_rule + (size_t)r * ED + e);
      acc[r] += w4.x * a4.x + w4.y * a4.y + w4.z * a4.z + w4.w * a4.w;
    }
  }
  #pragma unroll
  for (int r = 0; r < RD; r++) MT[(size_t)j * RD + r] = acc[r];
  float bb = b_ih[j] + b_hh[j];
  bias0[j]  = accb + bb;
  bias12[j] = bb;
}

// ---------------------------------------------------------------------------
// Kernel B: tiled TN GEMM  out[orow(i)][perm(j)] = sum_k Arow(i)[k]*B[j*K+k] + bias[j]
// mode 0: A=rules (lda=32,K=32), orow=3i            (rule timestep, B=MT)
// mode 1: A=face_table gathered, K=1024:
//         i<NS : id1[i],  orow=3i+1 ;  i>=NS : id2[i-NS], orow=3(i-NS)+2
// Output column permutation: j = g*1024 + h  ->  (h>>3)*32 + g*8 + (h&7)
// so RNN block b's 32 gate inputs per step are ONE contiguous 128B line.
// Tile 128x128, 256 threads, 8x8 per thread, K-chunk 32, LDS stored k-major.
// ---------------------------------------------------------------------------
__global__ __launch_bounds__(256) void gemm_kernel(
    const float* __restrict__ A, const float* __restrict__ B,
    const float* __restrict__ bias,
    const int* __restrict__ id1, const int* __restrict__ id2,
    float* __restrict__ out, int K, int mode)
{
  __shared__ float As[32][132];
  __shared__ float Bs[32][132];
  const int t  = threadIdx.x;
  const int lr = t >> 1;            // 0..127 tile row loaded by this thread
  const int lk = (t & 1) * 16;      // k-offset within chunk
  const int ti = t & 15;            // 16x16 thread grid
  const int tj = t >> 4;
  const int bi = blockIdx.x, bj = blockIdx.y;

  int gi = bi * 128 + lr;
  const float* arow;
  if (mode == 0) {
    arow = A + (size_t)gi * 32;
  } else {
    int idx = (gi < NS) ? id1[gi] : id2[gi - NS];
    arow = A + (size_t)idx * ED;
  }
  const float* brow = B + (size_t)(bj * 128 + lr) * K;

  float acc[8][8];
  #pragma unroll
  for (int i = 0; i < 8; i++)
    #pragma unroll
    for (int j = 0; j < 8; j++) acc[i][j] = 0.0f;

  for (int kc = 0; kc < K; kc += 32) {
    float4 a0 = *(const float4*)(arow + kc + lk);
    float4 a1 = *(const float4*)(arow + kc + lk + 4);
    float4 a2 = *(const float4*)(arow + kc + lk + 8);
    float4 a3 = *(const float4*)(arow + kc + lk + 12);
    float4 b0 = *(const float4*)(brow + kc + lk);
    float4 b1 = *(const float4*)(brow + kc + lk + 4);
    float4 b2 = *(const float4*)(brow + kc + lk + 8);
    float4 b3 = *(const float4*)(brow + kc + lk + 12);
    __syncthreads();
    As[lk+ 0][lr]=a0.x; As[lk+ 1][lr]=a0.y; As[lk+ 2][lr]=a0.z; As[lk+ 3][lr]=a0.w;
    As[lk+ 4][lr]=a1.x; As[lk+ 5][lr]=a1.y; As[lk+ 6][lr]=a1.z; As[lk+ 7][lr]=a1.w;
    As[lk+ 8][lr]=a2.x; As[lk+ 9][lr]=a2.y; As[lk+10][lr]=a2.z; As[lk+11][lr]=a2.w;
    As[lk+12][lr]=a3.x; As[lk+13][lr]=a3.y; As[lk+14][lr]=a3.z; As[lk+15][lr]=a3.w;
    Bs[lk+ 0][lr]=b0.x; Bs[lk+ 1][lr]=b0.y; Bs[lk+ 2][lr]=b0.z; Bs[lk+ 3][lr]=b0.w;
    Bs[lk+ 4][lr]=b1.x; Bs[lk+ 5][lr]=b1.y; Bs[lk+ 6][lr]=b1.z; Bs[lk+ 7][lr]=b1.w;
    Bs[lk+ 8][lr]=b2.x; Bs[lk+ 9][lr]=b2.y; Bs[lk+10][lr]=b2.z; Bs[lk+11][lr]=b2.w;
    Bs[lk+12][lr]=b3.x; Bs[lk+13][lr]=b3.y; Bs[lk+14][lr]=b3.z; Bs[lk+15][lr]=b3.w;
    __syncthreads();
    #pragma unroll
    for (int kk = 0; kk < 32; kk++) {
      float av[8], bv[8];
      *(float4*)&av[0] = *(const float4*)&As[kk][ti * 8];
      *(float4*)&av[4] = *(const float4*)&As[kk][ti * 8 + 4];
      *(float4*)&bv[0] = *(const float4*)&Bs[kk][tj * 8];
      *(float4*)&bv[4] = *(const float4*)&Bs[kk][tj * 8 + 4];
      #pragma unroll
      for (int i = 0; i < 8; i++)
        #pragma unroll
        for (int j = 0; j < 8; j++)
          acc[i][j] += av[i] * bv[j];
    }
  }

  int j0 = bj * 128 + tj * 8;       // 8-aligned, single gate block g (128 | 1024)
  float bsv[8];
  *(float4*)&bsv[0] = *(const float4*)(bias + j0);
  *(float4*)&bsv[4] = *(const float4*)(bias + j0 + 4);
  int g  = j0 >> 10;
  int h0 = j0 & 1023;               // 8-aligned h index
  size_t pj = (size_t)(h0 >> 3) * 32 + (size_t)g * 8;   // permuted column base
  #pragma unroll
  for (int i = 0; i < 8; i++) {
    int gi2 = bi * 128 + ti * 8 + i;
    size_t orow;
    if (mode == 0)      orow = (size_t)3 * gi2;
    else if (gi2 < NS)  orow = (size_t)3 * gi2 + 1;
    else                orow = (size_t)3 * (gi2 - NS) + 2;
    float4 o0 = make_float4(acc[i][0] + bsv[0], acc[i][1] + bsv[1],
                            acc[i][2] + bsv[2], acc[i][3] + bsv[3]);
    float4 o1 = make_float4(acc[i][4] + bsv[4], acc[i][5] + bsv[5],
                            acc[i][6] + bsv[6], acc[i][7] + bsv[7]);
    *(float4*)(out + orow * G4 + pj)     = o0;
    *(float4*)(out + orow * G4 + pj + 4) = o1;
  }
}

// ---------------------------------------------------------------------------
// Kernel C: persistent sequential LSTM. 128 blocks x 512 threads.
// Block b owns h-units [8b, 8b+8); wave w -> h-unit 8b+w (its 4 gate rows);
// lane holds 4x16 W_hh weights in VGPRs.
//
// Broadcast protocol (single coherent round trip, NO fences, NO flags):
// producer of unit u at step s stores ONE 64-bit relaxed agent atomic
// {tag = s+1 (hi 32), h bits (lo 32)} into ring[s&7][u].  Consumers poll the
// tagged value itself: data IS the readiness flag, so there is no separate
// flag line, no release-store drain, and no acquire buffer_inv per step
// (L2 stays warm for the xg stream).  Ring tags are cleared by prep_kernel
// each launch; block skew is <=1 step, so depth 8 cannot wrap.
// ---------------------------------------------------------------------------
__global__ __launch_bounds__(512) void rnn_kernel(
    const float* __restrict__ W_hh, const float* __restrict__ xg,
    unsigned long long* ring, float* __restrict__ hhist)
{
  const int b     = blockIdx.x;
  const int tid   = threadIdx.x;
  const int wave  = tid >> 6;
  const int lane  = tid & 63;
  const int hunit = b * 8 + wave;     // 0..1023
  const int kbase = lane * 16;

  // resident W_hh fragment: rows {g*1024+hunit}, k in [kbase, kbase+16)
  float w[4][16];
  #pragma unroll
  for (int g = 0; g < 4; g++) {
    const float* p = W_hh + ((size_t)(g * HD + hunit)) * HD + kbase;
    *(float4*)&w[g][0]  = *(const float4*)(p);
    *(float4*)&w[g][4]  = *(const float4*)(p + 4);
    *(float4*)&w[g][8]  = *(const float4*)(p + 8);
    *(float4*)&w[g][12] = *(const float4*)(p + 12);
  }

  __shared__ float hlds[1280];         // 1024 floats, +4 pad per 16 (bank-even b128)
  float c = 0.0f;                      // only lane 0 of each wave uses
  const int e0 = tid * 2;              // this thread stages h elems e0, e0+1

  for (int s = 0; s < TT; s++) {
    // prefetch this step's 4 gate inputs: one 128B line per block (overlaps poll)
    float xgv[4] = {0.f, 0.f, 0.f, 0.f};
    if (lane == 0) {
      const float* xp = xg + (size_t)s * G4 + (size_t)b * 32;
      xgv[0] = xp[wave]; xgv[1] = xp[8 + wave];
      xgv[2] = xp[16 + wave]; xgv[3] = xp[24 + wave];
    }

    // obtain h_{s-1}: poll tagged 64-bit values, stage into LDS
    if (s == 0) {
      hlds[PAD(e0)]     = 0.0f;
      hlds[PAD(e0 + 1)] = 0.0f;
    } else {
      const unsigned long long* rrow = ring + ((size_t)((s - 1) & (RING - 1)) << 10);
      const unsigned tgt = (unsigned)s;          // tag written at step s-1 is (s-1)+1
      unsigned long long u0, u1;
      for (;;) {
        u0 = __hip_atomic_load(&rrow[e0],     __ATOMIC_RELAXED, __HIP_MEMORY_SCOPE_AGENT);
        u1 = __hip_atomic_load(&rrow[e0 + 1], __ATOMIC_RELAXED, __HIP_MEMORY_SCOPE_AGENT);
        if ((unsigned)(u0 >> 32) == tgt && (unsigned)(u1 >> 32) == tgt) break;
        __builtin_amdgcn_s_sleep(1);
      }
      hlds[PAD(e0)]     = __uint_as_float((unsigned)u0);
      hlds[PAD(e0 + 1)] = __uint_as_float((unsigned)u1);
    }
    __syncthreads();

    float hq[16];
    const float* hp = &hlds[lane * 20];          // PAD(lane*16), 16B aligned
    *(float4*)&hq[0]  = *(const float4*)(hp);
    *(float4*)&hq[4]  = *(const float4*)(hp + 4);
    *(float4*)&hq[8]  = *(const float4*)(hp + 8);
    *(float4*)&hq[12] = *(const float4*)(hp + 12);

    float si = 0.f, sf = 0.f, sg = 0.f, so = 0.f;
    #pragma unroll
    for (int q = 0; q < 16; q++) {
      float h = hq[q];
      si += w[0][q] * h; sf += w[1][q] * h;
      sg += w[2][q] * h; so += w[3][q] * h;
    }
    #pragma unroll
    for (int off = 32; off > 0; off >>= 1) {
      si += __shfl_down(si, off);
      sf += __shfl_down(sf, off);
      sg += __shfl_down(sg, off);
      so += __shfl_down(so, off);
    }

    if (lane == 0) {
      float iv = sigm(si + xgv[0]);
      float fv = sigm(sf + xgv[1]);
      float gv = tanh_(sg + xgv[2]);
      float ov = sigm(so + xgv[3]);
      c = fv * c + iv * gv;
      float hv = ov * tanh_(c);
      unsigned long long pk =
          ((unsigned long long)(unsigned)(s + 1) << 32) |
          (unsigned long long)__float_as_uint(hv);
      __hip_atomic_store(&ring[((size_t)(s & (RING - 1)) << 10) + hunit], pk,
                         __ATOMIC_RELAXED, __HIP_MEMORY_SCOPE_AGENT);
      if (s % 3 == 2) hhist[(size_t)(s / 3) * HD + hunit] = hv;  // read post-kernel
    }
    __syncthreads();   // protect hlds reuse against fast waves starting s+1 staging
  }
}

// ---------------------------------------------------------------------------
// Kernel D: out[n][:2] = h_hist[n] @ W_out + b_out
// ---------------------------------------------------------------------------
__global__ __launch_bounds__(256) void out_kernel(
    const float* __restrict__ hhist, const float* __restrict__ W_out,
    const float* __restrict__ b_out, float* __restrict__ out)
{
  int n = blockIdx.x;
  int tid = threadIdx.x;
  const float* h = hhist + (size_t)n * HD;
  int k0 = tid * 4;
  float4 h4 = *(const float4*)(h + k0);
  float4 wa = *(const float4*)(W_out + (size_t)k0 * 2);      // (k0,j0..1),(k0+1,j0..1)
  float4 wb = *(const float4*)(W_out + (size_t)k0 * 2 + 4);  // (k0+2),(k0+3)
  float a0 = h4.x * wa.x + h4.y * wa.z + h4.z * wb.x + h4.w * wb.z;
  float a1 = h4.x * wa.y + h4.y * wa.w + h4.z * wb.y + h4.w * wb.w;
  #pragma unroll
  for (int off = 32; off > 0; off >>= 1) {
    a0 += __shfl_down(a0, off);
    a1 += __shfl_down(a1, off);
  }
  __shared__ float r0[4], r1[4];
  if ((tid & 63) == 0) { r0[tid >> 6] = a0; r1[tid >> 6] = a1; }
  __syncthreads();
  if (tid == 0) {
    out[(size_t)n * 2 + 0] = r0[0] + r0[1] + r0[2] + r0[3] + b_out[0];
    out[(size_t)n * 2 + 1] = r1[0] + r1[1] + r1[2] + r1[3] + b_out[1];
  }
}

// ---------------------------------------------------------------------------
extern "C" void kernel_launch(void* const* d_in, const int* in_sizes, int n_in,
                              void* d_out, int out_size, void* d_ws, size_t ws_size,
                              hipStream_t stream) {
  const float* rules  = (const float*)d_in[0];
  const int*   id1    = (const int*)  d_in[1];
  const int*   id2    = (const int*)  d_in[2];
  const float* W_rule = (const float*)d_in[3];
  const float* b_rule = (const float*)d_in[4];
  const float* face   = (const float*)d_in[5];
  const float* W_ih   = (const float*)d_in[6];
  const float* W_hh   = (const float*)d_in[7];
  const float* b_ih   = (const float*)d_in[8];
  const float* b_hh   = (const float*)d_in[9];
  const float* W_out  = (const float*)d_in[10];
  const float* b_out  = (const float*)d_in[11];
  float* out = (float*)d_out;

  // workspace carve-up (all 16B aligned)
  float* xg     = (float*)d_ws;                      // TT*G4      = 402.7 MB
  float* MT     = xg + (size_t)TT * G4;              // G4*RD      = 0.5 MB
  float* bias0  = MT + (size_t)G4 * RD;              // G4
  float* bias12 = bias0 + G4;                        // G4
  float* hhist  = bias12 + G4;                       // NS*HD      = 33.6 MB
  unsigned long long* ring = (unsigned long long*)(hhist + (size_t)NS * HD);
                                                     // RING*HD*8B = 64 KB

  prep_kernel<<<dim3(G4 / 256), dim3(256), 0, stream>>>(
      W_rule, b_rule, W_ih, b_ih, b_hh, MT, bias0, bias12, ring);

  gemm_kernel<<<dim3(NS / 128, G4 / 128), dim3(256), 0, stream>>>(
      rules, MT, bias0, id1, id2, xg, 32, 0);

  gemm_kernel<<<dim3(2 * NS / 128, G4 / 128), dim3(256), 0, stream>>>(
      face, W_ih, bias12, id1, id2, xg, ED, 1);

  rnn_kernel<<<dim3(NBLK), dim3(512), 0, stream>>>(W_hh, xg, ring, hhist);

  out_kernel<<<dim3(NS), dim3(256), 0, stream>>>(hhist, W_out, b_out, out);
}